// Round 10
// baseline (150.887 us; speedup 1.0000x reference)
//
#include <hip/hip_runtime.h>
#include <hip/hip_bf16.h>
#include <math.h>

typedef short short8 __attribute__((ext_vector_type(8)));
typedef float f32x4 __attribute__((ext_vector_type(4)));
typedef int i32x4 __attribute__((ext_vector_type(4)));

#define NN 8192
#define FIN 256
#define FOUT 128
#define LRELU_A 0.2f
#define L2E 1.44269504088896f

__device__ __forceinline__ short f2bf(float x) {
    unsigned u = __builtin_bit_cast(unsigned, x);
    unsigned r = (u + 0x7FFFu + ((u >> 16) & 1u)) >> 16;   // RNE
    return (short)r;
}

// K1: Wh = h @ W (fp32), fused f1 = Wh@a1, f2 = Wh@a2.
__global__ __launch_bounds__(256) void k_wh(const float* __restrict__ h,
                                            const float* __restrict__ W,
                                            const float* __restrict__ a,
                                            float* __restrict__ Wh,
                                            float* __restrict__ f1,
                                            float* __restrict__ f2) {
    __shared__ float hs[8][FIN];
    const int tid = threadIdx.x;
    const int r0 = blockIdx.x * 8;
    #pragma unroll
    for (int i = 0; i < 2; ++i) {
        int f4 = tid + 256 * i;
        int row = f4 >> 6;
        int k4 = (f4 & 63) << 2;
        *(float4*)&hs[row][k4] = *(const float4*)(h + (size_t)(r0 + row) * FIN + k4);
    }
    __syncthreads();
    const int c4 = (tid & 31) * 4;
    const int row = tid >> 5;
    float acc0 = 0.f, acc1 = 0.f, acc2 = 0.f, acc3 = 0.f;
    #pragma unroll 4
    for (int k = 0; k < FIN; ++k) {
        float hv = hs[row][k];
        float4 w4 = *(const float4*)(W + (size_t)k * FOUT + c4);
        acc0 = fmaf(hv, w4.x, acc0);
        acc1 = fmaf(hv, w4.y, acc1);
        acc2 = fmaf(hv, w4.z, acc2);
        acc3 = fmaf(hv, w4.w, acc3);
    }
    float4 o; o.x = acc0; o.y = acc1; o.z = acc2; o.w = acc3;
    *(float4*)(Wh + (size_t)(r0 + row) * FOUT + c4) = o;

    float4 a1v = *(const float4*)(a + c4);
    float4 a2v = *(const float4*)(a + FOUT + c4);
    float p1 = acc0 * a1v.x + acc1 * a1v.y + acc2 * a1v.z + acc3 * a1v.w;
    float p2 = acc0 * a2v.x + acc1 * a2v.y + acc2 * a2v.z + acc3 * a2v.w;
    #pragma unroll
    for (int m = 1; m <= 16; m <<= 1) {
        p1 += __shfl_xor(p1, m, 64);
        p2 += __shfl_xor(p2, m, 64);
    }
    if ((tid & 31) == 0) {
        f1[r0 + row] = p1;
        f2[r0 + row] = p2;
    }
}

// K1t: WhT[c][r] = bf16(Wh[r][c]) via 32x32 LDS tiles.
__global__ __launch_bounds__(256) void k_transpose(const float* __restrict__ Wh,
                                                   short* __restrict__ WhT) {
    __shared__ float t32[32][33];
    const int tid = threadIdx.x;
    const int tx = tid & 31, ty = tid >> 5;
    const int rb = (blockIdx.x & 255) * 32;
    const int cb = (blockIdx.x >> 8) * 32;
    #pragma unroll
    for (int q = 0; q < 4; ++q) {
        int r = ty + q * 8;
        t32[r][tx] = Wh[(size_t)(rb + r) * FOUT + cb + tx];
    }
    __syncthreads();
    #pragma unroll
    for (int q = 0; q < 4; ++q) {
        int c = ty + q * 8;
        WhT[(size_t)(cb + c) * NN + rb + tx] = f2bf(t32[tx][c]);
    }
}

// K1c: gmax = max(f2)
__global__ __launch_bounds__(256) void k_gmax(const float* __restrict__ f2,
                                              float* __restrict__ gmax) {
    const int tid = threadIdx.x;
    float m = -1e30f;
    for (int i = tid; i < NN; i += 256) m = fmaxf(m, f2[i]);
    #pragma unroll
    for (int s = 1; s <= 32; s <<= 1) m = fmaxf(m, __shfl_xor(m, s, 64));
    __shared__ float red[4];
    if ((tid & 63) == 0) red[tid >> 6] = m;
    __syncthreads();
    if (tid == 0) gmax[0] = fmaxf(fmaxf(red[0], red[1]), fmaxf(red[2], red[3]));
}

__device__ __forceinline__ void gat_body(const short* __restrict__ lrd, unsigned m8,
                                         float4 fa, float4 fb,
                                         float f1r, float mh2, float& den,
                                         f32x4 acc[8]) {
    short8 b0 = *(const short8*)(lrd + 0 * 1024);
    short8 b1 = *(const short8*)(lrd + 1 * 1024);
    short8 b2 = *(const short8*)(lrd + 2 * 1024);
    short8 b3 = *(const short8*)(lrd + 3 * 1024);
    short8 b4 = *(const short8*)(lrd + 4 * 1024);
    short8 b5 = *(const short8*)(lrd + 5 * 1024);
    short8 b6 = *(const short8*)(lrd + 6 * 1024);
    short8 b7 = *(const short8*)(lrd + 7 * 1024);

    float fv[8] = {fa.x, fa.y, fa.z, fa.w, fb.x, fb.y, fb.z, fb.w};
    short8 af;
    #pragma unroll
    for (int i = 0; i < 8; ++i) {
        float e = f1r + fv[i];
        e = fmaxf(e, LRELU_A * e);
        float p = __builtin_amdgcn_exp2f(fmaf(e, L2E, -mh2));
        p = (m8 & (1u << i)) ? p : 0.0f;
        den += p;
        af[i] = f2bf(p);
    }
    acc[0] = __builtin_amdgcn_mfma_f32_16x16x32_bf16(af, b0, acc[0], 0, 0, 0);
    acc[1] = __builtin_amdgcn_mfma_f32_16x16x32_bf16(af, b1, acc[1], 0, 0, 0);
    acc[2] = __builtin_amdgcn_mfma_f32_16x16x32_bf16(af, b2, acc[2], 0, 0, 0);
    acc[3] = __builtin_amdgcn_mfma_f32_16x16x32_bf16(af, b3, acc[3], 0, 0, 0);
    acc[4] = __builtin_amdgcn_mfma_f32_16x16x32_bf16(af, b4, acc[4], 0, 0, 0);
    acc[5] = __builtin_amdgcn_mfma_f32_16x16x32_bf16(af, b5, acc[5], 0, 0, 0);
    acc[6] = __builtin_amdgcn_mfma_f32_16x16x32_bf16(af, b6, acc[6], 0, 0, 0);
    acc[7] = __builtin_amdgcn_mfma_f32_16x16x32_bf16(af, b7, acc[7], 0, 0, 0);
}

// One pipeline step (64 cols). Masks from X regs (adj loaded 2 steps ago);
// reissue adj loads for step s+2; stage WhT tile s+1 (full-line reg loads,
// ds_write at step end); f2 from LDS; one lgkm-only barrier per step.
// No sched_barrier: the compiler's counted vmcnt before the ds_writes keeps
// the adj prefetch (newest VMEM ops) in flight across the barrier.
#define GAT_STEP(KOFF, X0, X1, X2, X3, LRD0, LRD1, BUFW)                           \
    {                                                                              \
        const int koff_ = (KOFF);                                                  \
        float4 fa0 = *(const float4*)(lf2 + koff_);                                \
        float4 fb0 = *(const float4*)(lf2 + koff_ + 4);                            \
        float4 fa1 = *(const float4*)(lf2 + koff_ + 32);                           \
        float4 fb1 = *(const float4*)(lf2 + koff_ + 36);                           \
        unsigned m0 = (unsigned)(X0.x & 1)        | ((unsigned)(X0.y & 1) << 1) |  \
                      ((unsigned)(X0.z & 1) << 2) | ((unsigned)(X0.w & 1) << 3) |  \
                      ((unsigned)(X1.x & 1) << 4) | ((unsigned)(X1.y & 1) << 5) |  \
                      ((unsigned)(X1.z & 1) << 6) | ((unsigned)(X1.w & 1) << 7);   \
        unsigned m1 = (unsigned)(X2.x & 1)        | ((unsigned)(X2.y & 1) << 1) |  \
                      ((unsigned)(X2.z & 1) << 2) | ((unsigned)(X2.w & 1) << 3) |  \
                      ((unsigned)(X3.x & 1) << 4) | ((unsigned)(X3.y & 1) << 5) |  \
                      ((unsigned)(X3.z & 1) << 6) | ((unsigned)(X3.w & 1) << 7);   \
        const int kpre_ = (koff_ + 128 < kchunk) ? koff_ + 128 : 0;                \
        X0 = *(const i32x4*)(adjp + kpre_);                                        \
        X1 = *(const i32x4*)(adjp + kpre_ + 4);                                    \
        X2 = *(const i32x4*)(adjp + kpre_ + 32);                                   \
        X3 = *(const i32x4*)(adjp + kpre_ + 36);                                   \
        const int kst_ = (koff_ + 64 < kchunk) ? koff_ + 64 : 0;                   \
        short8 r0 = *(const short8*)(g00 + kst_);                                  \
        short8 r1 = *(const short8*)(g01 + kst_);                                  \
        short8 r2 = *(const short8*)(g10 + kst_);                                  \
        short8 r3 = *(const short8*)(g11 + kst_);                                  \
        gat_body(LRD0, m0, fa0, fb0, f1r, mh2, den, acc);                          \
        gat_body(LRD1, m1, fa1, fb1, f1r, mh2, den, acc);                          \
        *(short8*)((BUFW) + d00) = r0;                                             \
        *(short8*)((BUFW) + d01) = r1;                                             \
        *(short8*)((BUFW) + d10) = r2;                                             \
        *(short8*)((BUFW) + d11) = r3;                                             \
        asm volatile("s_waitcnt lgkmcnt(0)" ::: "memory");                         \
        __builtin_amdgcn_s_barrier();                                              \
    }

// K2: fused mask + leaky_relu + exp + (P @ Wh) via mfma_f32_16x16x32_bf16.
// adj streamed directly (exactly-once traffic), hidden under the
// latency/VALU-bound step pipeline.
__global__ __launch_bounds__(256, 4) void k_attn(const int* __restrict__ adj,
                                                 const short* __restrict__ WhT,
                                                 const float* __restrict__ f1,
                                                 const float* __restrict__ f2,
                                                 const float* __restrict__ gmax,
                                                 float* __restrict__ numb,
                                                 float* __restrict__ denb,
                                                 int kchunk, int nsplit) {
    __shared__ __align__(16) short ldsW[2][8192];   // 2 x [128 rows][64 cols], swizzled
    __shared__ __align__(16) float ldsF2[2048];
    const int tid = threadIdx.x;
    const int lane = tid & 63;
    const int wave = tid >> 6;
    const int split = blockIdx.x & (nsplit - 1);
    const int rt = blockIdx.x / nsplit;
    const int rowbase = rt * 64 + wave * 16;
    const int col = lane & 15;
    const int kg = lane >> 4;
    const int arow = rowbase + col;

    const float f1r = f1[arow];
    const float gm = gmax[0];
    const float t0v = f1r + gm;
    const float mhat = fmaxf(t0v, LRELU_A * t0v);   // row-max upper bound
    const float mh2 = mhat * L2E;

    const int kbase0 = split * kchunk;
    const int* adjp = adj + (size_t)arow * NN + kbase0 + kg * 8;
    const float* lf2 = ldsF2 + kg * 8;

    // full-line W staging: row = wave*32 + (lane>>2), 16 rows x 64B/inst.
    const int srow = wave * 32 + (lane >> 2);
    const int sx = srow & 7;
    const short* gsb = WhT + (size_t)srow * NN + kbase0 + (lane & 3) * 8;
    const short* g00 = gsb;
    const short* g01 = gsb + 32;
    const short* g10 = gsb + (size_t)16 * NN;
    const short* g11 = gsb + (size_t)16 * NN + 32;
    const int d00 = srow * 64        + ((((lane & 3) + 0) ^ sx) * 8);
    const int d01 = srow * 64        + ((((lane & 3) + 4) ^ sx) * 8);
    const int d10 = (srow + 16) * 64 + ((((lane & 3) + 0) ^ sx) * 8);
    const int d11 = (srow + 16) * 64 + ((((lane & 3) + 4) ^ sx) * 8);
    short* buf0 = &ldsW[0][0];
    short* buf1 = &ldsW[1][0];

    // compute-read bases (body0 / body1 within a 64-col tile)
    const short* lrdE0 = &ldsW[0][col * 64 + ((kg ^ (col & 7)) * 8)];
    const short* lrdE1 = &ldsW[0][col * 64 + (((kg ^ (col & 7)) * 8) ^ 32)];
    const short* lrdO0 = lrdE0 + 8192;
    const short* lrdO1 = lrdE1 + 8192;

    f32x4 acc[8] = {};
    float den = 0.0f;

    // prologue: f2 slice -> LDS; W tile0 -> buf0; adj for steps 0 and 1
    for (int i = tid * 4; i < kchunk; i += 1024)
        *(float4*)&ldsF2[i] = *(const float4*)(f2 + kbase0 + i);
    {
        short8 r0 = *(const short8*)(g00);
        short8 r1 = *(const short8*)(g01);
        short8 r2 = *(const short8*)(g10);
        short8 r3 = *(const short8*)(g11);
        *(short8*)(buf0 + d00) = r0;
        *(short8*)(buf0 + d01) = r1;
        *(short8*)(buf0 + d10) = r2;
        *(short8*)(buf0 + d11) = r3;
    }
    i32x4 xa0 = *(const i32x4*)(adjp + 0);
    i32x4 xa1 = *(const i32x4*)(adjp + 4);
    i32x4 xa2 = *(const i32x4*)(adjp + 32);
    i32x4 xa3 = *(const i32x4*)(adjp + 36);
    i32x4 xb0 = *(const i32x4*)(adjp + 64);
    i32x4 xb1 = *(const i32x4*)(adjp + 68);
    i32x4 xb2 = *(const i32x4*)(adjp + 96);
    i32x4 xb3 = *(const i32x4*)(adjp + 100);
    asm volatile("s_waitcnt lgkmcnt(0)" ::: "memory");
    __builtin_amdgcn_s_barrier();

    for (int koff = 0; koff < kchunk; koff += 128) {
        GAT_STEP(koff,      xa0, xa1, xa2, xa3, lrdE0, lrdE1, buf1);   // compute buf0
        GAT_STEP(koff + 64, xb0, xb1, xb2, xb3, lrdO0, lrdO1, buf0);   // compute buf1
    }

    // reduce den across the 4 kg groups
    den += __shfl_xor(den, 16, 64);
    den += __shfl_xor(den, 32, 64);
    if (lane < 16) denb[(size_t)split * NN + rowbase + lane] = den;

    float* np = numb + ((size_t)split * NN + rowbase) * FOUT;
    const int rsub = (lane >> 4) * 4;
    #pragma unroll
    for (int t = 0; t < 8; ++t) {
        #pragma unroll
        for (int r = 0; r < 4; ++r) {
            np[(size_t)(rsub + r) * FOUT + t * 16 + col] = acc[t][r];
        }
    }
}

// K3: sum split partials, divide, ELU.
__global__ __launch_bounds__(256) void k_final(const float* __restrict__ numb,
                                               const float* __restrict__ denb,
                                               float* __restrict__ out,
                                               int splitk) {
    const int idx = blockIdx.x * 256 + threadIdx.x;
    const int row = idx >> 7;
    float s = 0.0f, d = 0.0f;
    for (int sp = 0; sp < splitk; ++sp) {
        s += numb[((size_t)sp * NN) * FOUT + idx];
        d += denb[(size_t)sp * NN + row];
    }
    float v = s / d;
    out[idx] = v > 0.0f ? v : expm1f(v);
}

extern "C" void kernel_launch(void* const* d_in, const int* in_sizes, int n_in,
                              void* d_out, int out_size, void* d_ws, size_t ws_size,
                              hipStream_t stream) {
    const float* h = (const float*)d_in[0];
    const int* adj = (const int*)d_in[1];
    const float* W = (const float*)d_in[2];
    const float* a = (const float*)d_in[3];
    float* out = (float*)d_out;

    char* ws = (char*)d_ws;
    size_t off = 0;
    auto alloc = [&](size_t nbytes) {
        char* p = ws + off;
        off = (off + nbytes + 255) & ~(size_t)255;
        return p;
    };
    float* Wh  = (float*)alloc((size_t)NN * FOUT * 4);
    short* WhT = (short*)alloc((size_t)FOUT * NN * 2);
    float* f1  = (float*)alloc(NN * 4);
    float* f2  = (float*)alloc(NN * 4);
    float* gmx = (float*)alloc(256);

    int splitk = 8;
    while (splitk > 1 &&
           off + (size_t)splitk * ((size_t)NN * FOUT * 4 + NN * 4 + 512) > ws_size)
        splitk >>= 1;
    float* numb = (float*)alloc((size_t)splitk * NN * FOUT * 4);
    float* denb = (float*)alloc((size_t)splitk * NN * 4);
    const int kchunk = NN / splitk;

    k_wh<<<NN / 8, 256, 0, stream>>>(h, W, a, Wh, f1, f2);
    k_transpose<<<(NN / 32) * (FOUT / 32), 256, 0, stream>>>(Wh, WhT);
    k_gmax<<<1, 256, 0, stream>>>(f2, gmx);
    k_attn<<<(NN / 64) * splitk, 256, 0, stream>>>(adj, WhT, f1, f2, gmx, numb, denb,
                                                   kchunk, splitk);
    k_final<<<NN * FOUT / 256, 256, 0, stream>>>(numb, denb, out, splitk);
}

// Round 11
// 132.828 us; speedup vs baseline: 1.1360x; 1.1360x over previous
//
#include <hip/hip_runtime.h>
#include <hip/hip_bf16.h>
#include <math.h>

typedef short short8 __attribute__((ext_vector_type(8)));
typedef float f32x4 __attribute__((ext_vector_type(4)));
typedef int i32x4 __attribute__((ext_vector_type(4)));

#define NN 8192
#define FIN 256
#define FOUT 128
#define LRELU_A 0.2f
#define L2E 1.44269504088896f

__device__ __forceinline__ short f2bf(float x) {
    unsigned u = __builtin_bit_cast(unsigned, x);
    unsigned r = (u + 0x7FFFu + ((u >> 16) & 1u)) >> 16;   // RNE
    return (short)r;
}

__device__ __forceinline__ short f2bf_fast(float x) {
    return __builtin_bit_cast(short, __float2bfloat16(x));
}

// K0: pack adj -> bitmask, fully coalesced (1KB contiguous per wave-inst).
__global__ __launch_bounds__(256) void k_pack(const int* __restrict__ adj,
                                              unsigned* __restrict__ packed) {
    __shared__ unsigned char nib[2048];
    const int row = blockIdx.x;
    const int tid = threadIdx.x;
    const i32x4* base = (const i32x4*)(adj + (size_t)row * NN);
    #pragma unroll
    for (int q = 0; q < 8; ++q) {
        int idx = q * 256 + tid;
        i32x4 v = __builtin_nontemporal_load(base + idx);
        unsigned b = (unsigned)(v.x & 1)        | ((unsigned)(v.y & 1) << 1) |
                     ((unsigned)(v.z & 1) << 2) | ((unsigned)(v.w & 1) << 3);
        nib[idx] = (unsigned char)b;
    }
    __syncthreads();
    unsigned long long n8 = *(const unsigned long long*)&nib[tid * 8];
    unsigned w = 0;
    #pragma unroll
    for (int j = 0; j < 8; ++j)
        w |= ((unsigned)((n8 >> (8 * j)) & 0xFull)) << (4 * j);
    packed[(size_t)row * (NN / 32) + tid] = w;
}

// K1: Wh = h @ W (fp32); writes WhT (bf16, col-major) directly; f1, f2.
__global__ __launch_bounds__(256) void k_wh(const float* __restrict__ h,
                                            const float* __restrict__ W,
                                            const float* __restrict__ a,
                                            short* __restrict__ WhT,
                                            float* __restrict__ f1,
                                            float* __restrict__ f2) {
    __shared__ float hs[8][FIN];
    const int tid = threadIdx.x;
    const int r0 = blockIdx.x * 8;
    #pragma unroll
    for (int i = 0; i < 2; ++i) {
        int f4 = tid + 256 * i;
        int row = f4 >> 6;
        int k4 = (f4 & 63) << 2;
        *(float4*)&hs[row][k4] = *(const float4*)(h + (size_t)(r0 + row) * FIN + k4);
    }
    __syncthreads();
    const int c4 = (tid & 31) * 4;
    const int row = tid >> 5;
    float acc0 = 0.f, acc1 = 0.f, acc2 = 0.f, acc3 = 0.f;
    #pragma unroll 4
    for (int k = 0; k < FIN; ++k) {
        float hv = hs[row][k];
        float4 w4 = *(const float4*)(W + (size_t)k * FOUT + c4);
        acc0 = fmaf(hv, w4.x, acc0);
        acc1 = fmaf(hv, w4.y, acc1);
        acc2 = fmaf(hv, w4.z, acc2);
        acc3 = fmaf(hv, w4.w, acc3);
    }
    const int wr = r0 + row;
    WhT[(size_t)(c4 + 0) * NN + wr] = f2bf(acc0);
    WhT[(size_t)(c4 + 1) * NN + wr] = f2bf(acc1);
    WhT[(size_t)(c4 + 2) * NN + wr] = f2bf(acc2);
    WhT[(size_t)(c4 + 3) * NN + wr] = f2bf(acc3);

    float4 a1v = *(const float4*)(a + c4);
    float4 a2v = *(const float4*)(a + FOUT + c4);
    float p1 = acc0 * a1v.x + acc1 * a1v.y + acc2 * a1v.z + acc3 * a1v.w;
    float p2 = acc0 * a2v.x + acc1 * a2v.y + acc2 * a2v.z + acc3 * a2v.w;
    #pragma unroll
    for (int m = 1; m <= 16; m <<= 1) {
        p1 += __shfl_xor(p1, m, 64);
        p2 += __shfl_xor(p2, m, 64);
    }
    if ((tid & 31) == 0) {
        f1[wr] = p1;
        f2[wr] = p2;
    }
}

// K1c: gmax = max(f2)
__global__ __launch_bounds__(256) void k_gmax(const float* __restrict__ f2,
                                              float* __restrict__ gmax) {
    const int tid = threadIdx.x;
    float m = -1e30f;
    for (int i = tid; i < NN; i += 256) m = fmaxf(m, f2[i]);
    #pragma unroll
    for (int s = 1; s <= 32; s <<= 1) m = fmaxf(m, __shfl_xor(m, s, 64));
    __shared__ float red[4];
    if ((tid & 63) == 0) red[tid >> 6] = m;
    __syncthreads();
    if (tid == 0) gmax[0] = fmaxf(fmaxf(red[0], red[1]), fmaxf(red[2], red[3]));
}

// body: 32 cols. u = fv+c1, v = fma(0.2,fv,c2), p = exp2(max(u,v)), mask,
// bf16; 8 MFMA into acc[0..7] + 1 MFMA with ones into acc[8] (den = P@1).
__device__ __forceinline__ void gat_body(const short* __restrict__ lrd, unsigned m8,
                                         float4 fa, float4 fb,
                                         float c1, float c2,
                                         f32x4 acc[9], short8 ones) {
    short8 b0 = *(const short8*)(lrd + 0 * 1024);
    short8 b1 = *(const short8*)(lrd + 1 * 1024);
    short8 b2 = *(const short8*)(lrd + 2 * 1024);
    short8 b3 = *(const short8*)(lrd + 3 * 1024);
    short8 b4 = *(const short8*)(lrd + 4 * 1024);
    short8 b5 = *(const short8*)(lrd + 5 * 1024);
    short8 b6 = *(const short8*)(lrd + 6 * 1024);
    short8 b7 = *(const short8*)(lrd + 7 * 1024);

    float fv[8] = {fa.x, fa.y, fa.z, fa.w, fb.x, fb.y, fb.z, fb.w};
    short8 af;
    #pragma unroll
    for (int i = 0; i < 8; ++i) {
        float u = fv[i] + c1;
        float v = fmaf(LRELU_A, fv[i], c2);
        float p = __builtin_amdgcn_exp2f(fmaxf(u, v));
        p = (m8 & (1u << i)) ? p : 0.0f;
        af[i] = f2bf_fast(p);
    }
    acc[0] = __builtin_amdgcn_mfma_f32_16x16x32_bf16(af, b0, acc[0], 0, 0, 0);
    acc[1] = __builtin_amdgcn_mfma_f32_16x16x32_bf16(af, b1, acc[1], 0, 0, 0);
    acc[2] = __builtin_amdgcn_mfma_f32_16x16x32_bf16(af, b2, acc[2], 0, 0, 0);
    acc[3] = __builtin_amdgcn_mfma_f32_16x16x32_bf16(af, b3, acc[3], 0, 0, 0);
    acc[4] = __builtin_amdgcn_mfma_f32_16x16x32_bf16(af, b4, acc[4], 0, 0, 0);
    acc[5] = __builtin_amdgcn_mfma_f32_16x16x32_bf16(af, b5, acc[5], 0, 0, 0);
    acc[6] = __builtin_amdgcn_mfma_f32_16x16x32_bf16(af, b6, acc[6], 0, 0, 0);
    acc[7] = __builtin_amdgcn_mfma_f32_16x16x32_bf16(af, b7, acc[7], 0, 0, 0);
    acc[8] = __builtin_amdgcn_mfma_f32_16x16x32_bf16(af, ones, acc[8], 0, 0, 0);
}

// One pipeline step (64 cols): masks from packed word pair (prefetched last
// step); stage next WhT tile (full-line reg loads -> ds_write at step end);
// f2*L2E from LDS; one lgkm-only barrier per step.
#define GAT_STEP(KOFF, MC, LRD0, LRD1, BUFW)                                       \
    {                                                                              \
        const int koff_ = (KOFF);                                                  \
        float4 fa0 = *(const float4*)(lf2 + koff_);                                \
        float4 fb0 = *(const float4*)(lf2 + koff_ + 4);                            \
        float4 fa1 = *(const float4*)(lf2 + koff_ + 32);                           \
        float4 fb1 = *(const float4*)(lf2 + koff_ + 36);                           \
        unsigned m0 = (MC.x >> mshift) & 0xffu;                                    \
        unsigned m1 = (MC.y >> mshift) & 0xffu;                                    \
        const int kpm_ = (koff_ + 128 < kchunk) ? koff_ + 128 : 0;                 \
        MC = *(const uint2*)(pkrow + (kpm_ >> 5));                                 \
        const int kst_ = (koff_ + 64 < kchunk) ? koff_ + 64 : 0;                   \
        short8 r0 = *(const short8*)(g00 + kst_);                                  \
        short8 r1 = *(const short8*)(g01 + kst_);                                  \
        short8 r2 = *(const short8*)(g10 + kst_);                                  \
        short8 r3 = *(const short8*)(g11 + kst_);                                  \
        gat_body(LRD0, m0, fa0, fb0, c1, c2, acc, ones);                           \
        gat_body(LRD1, m1, fa1, fb1, c1, c2, acc, ones);                           \
        *(short8*)((BUFW) + d00) = r0;                                             \
        *(short8*)((BUFW) + d01) = r1;                                             \
        *(short8*)((BUFW) + d10) = r2;                                             \
        *(short8*)((BUFW) + d11) = r3;                                             \
        asm volatile("s_waitcnt lgkmcnt(0)" ::: "memory");                         \
        __builtin_amdgcn_s_barrier();                                              \
    }

// K2: fused mask + leaky_relu + exp + (P @ Wh) via mfma_f32_16x16x32_bf16.
__global__ __launch_bounds__(256, 4) void k_attn(const unsigned* __restrict__ packed,
                                                 const short* __restrict__ WhT,
                                                 const float* __restrict__ f1,
                                                 const float* __restrict__ f2,
                                                 const float* __restrict__ gmax,
                                                 float* __restrict__ numb,
                                                 float* __restrict__ denb,
                                                 int kchunk, int nsplit) {
    __shared__ __align__(16) short ldsW[2][8192];   // 2 x [128 rows][64 cols], swizzled
    __shared__ __align__(16) float ldsF2[2048];     // f2 * L2E
    const int tid = threadIdx.x;
    const int lane = tid & 63;
    const int wave = tid >> 6;
    const int split = blockIdx.x & (nsplit - 1);
    const int rt = blockIdx.x / nsplit;
    const int rowbase = rt * 64 + wave * 16;
    const int col = lane & 15;
    const int kg = lane >> 4;
    const int arow = rowbase + col;

    const float f1r = f1[arow];
    const float gm = gmax[0];
    const float t0v = f1r + gm;
    const float mhat = fmaxf(t0v, LRELU_A * t0v);   // row-max upper bound
    const float mh2 = mhat * L2E;
    const float c1 = fmaf(f1r, L2E, -mh2);
    const float c2 = fmaf(LRELU_A * f1r, L2E, -mh2);

    const short8 ones = {0x3F80, 0x3F80, 0x3F80, 0x3F80,
                         0x3F80, 0x3F80, 0x3F80, 0x3F80};   // bf16 1.0

    const int kbase0 = split * kchunk;
    const unsigned* pkrow = packed + (size_t)arow * (NN / 32) + (kbase0 >> 5);
    const int mshift = kg * 8;
    const float* lf2 = ldsF2 + kg * 8;

    // full-line W staging: row = wave*32 + (lane>>2), 16 rows x 64B/inst.
    const int srow = wave * 32 + (lane >> 2);
    const int sx = srow & 7;
    const short* gsb = WhT + (size_t)srow * NN + kbase0 + (lane & 3) * 8;
    const short* g00 = gsb;
    const short* g01 = gsb + 32;
    const short* g10 = gsb + (size_t)16 * NN;
    const short* g11 = gsb + (size_t)16 * NN + 32;
    const int d00 = srow * 64        + ((((lane & 3) + 0) ^ sx) * 8);
    const int d01 = srow * 64        + ((((lane & 3) + 4) ^ sx) * 8);
    const int d10 = (srow + 16) * 64 + ((((lane & 3) + 0) ^ sx) * 8);
    const int d11 = (srow + 16) * 64 + ((((lane & 3) + 4) ^ sx) * 8);
    short* buf0 = &ldsW[0][0];
    short* buf1 = &ldsW[1][0];

    // compute-read bases (body0 / body1 within a 64-col tile)
    const short* lrdE0 = &ldsW[0][col * 64 + ((kg ^ (col & 7)) * 8)];
    const short* lrdE1 = &ldsW[0][col * 64 + (((kg ^ (col & 7)) * 8) ^ 32)];
    const short* lrdO0 = lrdE0 + 8192;
    const short* lrdO1 = lrdE1 + 8192;

    f32x4 acc[9] = {};

    // prologue: f2*L2E -> LDS; W tile0 -> buf0; mask pairs for tiles 0,1
    for (int i = tid * 4; i < kchunk; i += 1024) {
        float4 v = *(const float4*)(f2 + kbase0 + i);
        v.x *= L2E; v.y *= L2E; v.z *= L2E; v.w *= L2E;
        *(float4*)&ldsF2[i] = v;
    }
    {
        short8 r0 = *(const short8*)(g00);
        short8 r1 = *(const short8*)(g01);
        short8 r2 = *(const short8*)(g10);
        short8 r3 = *(const short8*)(g11);
        *(short8*)(buf0 + d00) = r0;
        *(short8*)(buf0 + d01) = r1;
        *(short8*)(buf0 + d10) = r2;
        *(short8*)(buf0 + d11) = r3;
    }
    uint2 mA = *(const uint2*)(pkrow);
    uint2 mB = *(const uint2*)(pkrow + 2);
    asm volatile("s_waitcnt lgkmcnt(0)" ::: "memory");
    __builtin_amdgcn_s_barrier();

    for (int koff = 0; koff < kchunk; koff += 128) {
        GAT_STEP(koff,      mA, lrdE0, lrdE1, buf1);   // compute buf0, stage buf1
        GAT_STEP(koff + 64, mB, lrdO0, lrdO1, buf0);   // compute buf1, stage buf0
    }

    const int rsub = (lane >> 4) * 4;
    // den = P @ ones: acc[8][r] holds den[rowbase+rsub+r] (any col; use col==0)
    if (col == 0) {
        #pragma unroll
        for (int r = 0; r < 4; ++r)
            denb[(size_t)split * NN + rowbase + rsub + r] = acc[8][r];
    }

    float* np = numb + ((size_t)split * NN + rowbase) * FOUT;
    #pragma unroll
    for (int t = 0; t < 8; ++t) {
        #pragma unroll
        for (int r = 0; r < 4; ++r) {
            np[(size_t)(rsub + r) * FOUT + t * 16 + col] = acc[t][r];
        }
    }
}

// K3: sum split partials, divide, ELU.
__global__ __launch_bounds__(256) void k_final(const float* __restrict__ numb,
                                               const float* __restrict__ denb,
                                               float* __restrict__ out,
                                               int splitk) {
    const int idx = blockIdx.x * 256 + threadIdx.x;
    const int row = idx >> 7;
    float s = 0.0f, d = 0.0f;
    for (int sp = 0; sp < splitk; ++sp) {
        s += numb[((size_t)sp * NN) * FOUT + idx];
        d += denb[(size_t)sp * NN + row];
    }
    float v = s / d;
    out[idx] = v > 0.0f ? v : expm1f(v);
}

extern "C" void kernel_launch(void* const* d_in, const int* in_sizes, int n_in,
                              void* d_out, int out_size, void* d_ws, size_t ws_size,
                              hipStream_t stream) {
    const float* h = (const float*)d_in[0];
    const int* adj = (const int*)d_in[1];
    const float* W = (const float*)d_in[2];
    const float* a = (const float*)d_in[3];
    float* out = (float*)d_out;

    char* ws = (char*)d_ws;
    size_t off = 0;
    auto alloc = [&](size_t nbytes) {
        char* p = ws + off;
        off = (off + nbytes + 255) & ~(size_t)255;
        return p;
    };
    short* WhT     = (short*)alloc((size_t)FOUT * NN * 2);
    float* f1      = (float*)alloc(NN * 4);
    float* f2      = (float*)alloc(NN * 4);
    float* gmx     = (float*)alloc(256);
    unsigned* pkd  = (unsigned*)alloc((size_t)NN * (NN / 32) * 4);   // 8 MB

    int splitk = 8;
    while (splitk > 1 &&
           off + (size_t)splitk * ((size_t)NN * FOUT * 4 + NN * 4 + 512) > ws_size)
        splitk >>= 1;
    float* numb = (float*)alloc((size_t)splitk * NN * FOUT * 4);
    float* denb = (float*)alloc((size_t)splitk * NN * 4);
    const int kchunk = NN / splitk;

    k_wh<<<NN / 8, 256, 0, stream>>>(h, W, a, WhT, f1, f2);
    k_gmax<<<1, 256, 0, stream>>>(f2, gmx);
    k_pack<<<NN, 256, 0, stream>>>(adj, pkd);
    k_attn<<<(NN / 64) * splitk, 256, 0, stream>>>(pkd, WhT, f1, f2, gmx, numb, denb,
                                                   kchunk, splitk);
    k_final<<<NN * FOUT / 256, 256, 0, stream>>>(numb, denb, out, splitk);
}